// Round 1
// baseline (512.320 us; speedup 1.0000x reference)
//
#include <hip/hip_runtime.h>
#include <cstdint>
#include <cstddef>

#define N_FEAT 512
#define N_HID 64
#define N_CLASS 16
#define N_CLUSTER 32

// ---------------- degree / normalization ----------------
__global__ void k_deg_init(float* deg, int n) {
  int i = blockIdx.x * 256 + threadIdx.x;
  if (i < n) deg[i] = 1.0f;  // self-loop weight
}

__global__ void k_deg_acc(const int* __restrict__ col, const float* __restrict__ w,
                          float* __restrict__ deg, int E) {
  int i = blockIdx.x * 256 + threadIdx.x;
  if (i < E) atomicAdd(&deg[col[i]], w[i]);
}

__global__ void k_dinv(float* deg, int n) {
  int i = blockIdx.x * 256 + threadIdx.x;
  if (i < n) { float d = deg[i]; deg[i] = (d > 0.f) ? rsqrtf(d) : 0.f; }
}

// ---------------- tiled fp32 GEMM: C[M,64] = act(A[M,K]) @ B[K,64] ----------------
template<int K, bool RELU>
__global__ __launch_bounds__(256) void k_gemm64(
    const float* __restrict__ A, const float* __restrict__ B,
    float* __restrict__ C, int M) {
  __shared__ float As[64][68];   // pad 68: A-reads 2-way conflict max (free)
  __shared__ float Bs[64 * 64];
  const int t = threadIdx.x;
  const int row0 = blockIdx.x * 64;
  const int tr = t >> 4, tc = t & 15;
  float acc[4][4] = {{0.f}};

  for (int kc = 0; kc < K; kc += 64) {
    __syncthreads();
    // stage A tile: 64 rows x 64 k (float4, coalesced)
    #pragma unroll
    for (int i = 0; i < 4; ++i) {
      int f = t + i * 256;
      int r = f >> 4, k4 = f & 15;
      int row = row0 + r;
      float4 v = make_float4(0.f, 0.f, 0.f, 0.f);
      if (row < M) v = *(const float4*)&A[(size_t)row * K + kc + k4 * 4];
      if (RELU) {
        v.x = fmaxf(v.x, 0.f); v.y = fmaxf(v.y, 0.f);
        v.z = fmaxf(v.z, 0.f); v.w = fmaxf(v.w, 0.f);
      }
      *(float4*)&As[r][k4 * 4] = v;
    }
    // stage B tile: rows kc..kc+63, contiguous 4096 floats
    #pragma unroll
    for (int i = 0; i < 4; ++i) {
      int f = t + i * 256;
      ((float4*)Bs)[f] = ((const float4*)(B + (size_t)kc * 64))[f];
    }
    __syncthreads();
    #pragma unroll 16
    for (int k = 0; k < 64; ++k) {
      float a0 = As[tr * 4 + 0][k];
      float a1 = As[tr * 4 + 1][k];
      float a2 = As[tr * 4 + 2][k];
      float a3 = As[tr * 4 + 3][k];
      float4 b = *(const float4*)&Bs[k * 64 + tc * 4];
      acc[0][0] = fmaf(a0, b.x, acc[0][0]); acc[0][1] = fmaf(a0, b.y, acc[0][1]);
      acc[0][2] = fmaf(a0, b.z, acc[0][2]); acc[0][3] = fmaf(a0, b.w, acc[0][3]);
      acc[1][0] = fmaf(a1, b.x, acc[1][0]); acc[1][1] = fmaf(a1, b.y, acc[1][1]);
      acc[1][2] = fmaf(a1, b.z, acc[1][2]); acc[1][3] = fmaf(a1, b.w, acc[1][3]);
      acc[2][0] = fmaf(a2, b.x, acc[2][0]); acc[2][1] = fmaf(a2, b.y, acc[2][1]);
      acc[2][2] = fmaf(a2, b.z, acc[2][2]); acc[2][3] = fmaf(a2, b.w, acc[2][3]);
      acc[3][0] = fmaf(a3, b.x, acc[3][0]); acc[3][1] = fmaf(a3, b.y, acc[3][1]);
      acc[3][2] = fmaf(a3, b.z, acc[3][2]); acc[3][3] = fmaf(a3, b.w, acc[3][3]);
    }
  }
  #pragma unroll
  for (int i = 0; i < 4; ++i) {
    int row = row0 + tr * 4 + i;
    if (row < M) {
      float4 v = make_float4(acc[i][0], acc[i][1], acc[i][2], acc[i][3]);
      *(float4*)&C[(size_t)row * 64 + tc * 4] = v;
    }
  }
}

// ---------------- h init: h[i][:] = bias + xw[i][:] * dinv[i]^2 (self-loop folded in) ----------------
__global__ void k_init_h(const float* __restrict__ xw, const float* __restrict__ dinv,
                         const float* __restrict__ bias, float* __restrict__ h, int n) {
  int idx = blockIdx.x * 256 + threadIdx.x;   // one float4 per thread
  int i = idx >> 4, q = idx & 15;
  if (i >= n) return;
  float s = dinv[i]; s *= s;
  float4 v = *(const float4*)&xw[(size_t)i * 64 + q * 4];
  float4 bb = *(const float4*)&bias[q * 4];
  float4 o;
  o.x = fmaf(v.x, s, bb.x); o.y = fmaf(v.y, s, bb.y);
  o.z = fmaf(v.z, s, bb.z); o.w = fmaf(v.w, s, bb.w);
  *(float4*)&h[(size_t)i * 64 + q * 4] = o;
}

// ---------------- edge scatter: one wave (64 lanes) per edge ----------------
__global__ __launch_bounds__(256) void k_scatter(
    const int* __restrict__ rowi, const int* __restrict__ coli,
    const float* __restrict__ w, const float* __restrict__ dinv,
    const float* __restrict__ xw, float* __restrict__ h, int E) {
  int gid = blockIdx.x * 256 + threadIdx.x;
  int e = gid >> 6;
  int lane = gid & 63;
  if (e >= E) return;
  int r = rowi[e], c = coli[e];
  float coef = dinv[r] * w[e] * dinv[c];
  float val = xw[(size_t)r * 64 + lane] * coef;
  atomicAdd(&h[(size_t)c * 64 + lane], val);
}

// ---------------- fused FC head: out1 = h@fcW1+fb1, out2 = h@fcW2+fb2 ----------------
__global__ __launch_bounds__(256) void k_fc(
    const float* __restrict__ h,
    const float* __restrict__ fW1, const float* __restrict__ fb1,
    const float* __restrict__ fW2, const float* __restrict__ fb2,
    float* __restrict__ out, int M) {
  __shared__ float Hs[64][68];
  __shared__ float Ws[64][48];
  __shared__ float bs[48];
  const int t = threadIdx.x;
  const int row0 = blockIdx.x * 64;
  #pragma unroll
  for (int i = 0; i < 4; ++i) {
    int f = t + i * 256;
    int r = f >> 4, k4 = f & 15;
    int rr = row0 + r;
    float4 v = make_float4(0.f, 0.f, 0.f, 0.f);
    if (rr < M) v = *(const float4*)&h[(size_t)rr * 64 + k4 * 4];
    *(float4*)&Hs[r][k4 * 4] = v;
  }
  for (int f = t; f < 64 * 48; f += 256) {
    int k = f / 48, c = f - k * 48;
    Ws[k][c] = (c < 16) ? fW1[k * 16 + c] : fW2[k * 32 + (c - 16)];
  }
  if (t < 48) bs[t] = (t < 16) ? fb1[t] : fb2[t - 16];
  __syncthreads();
  const int tr = t >> 4, tc = t & 15;   // rows tr*4.., cols tc*3..
  float acc[4][3] = {{0.f}};
  #pragma unroll 8
  for (int k = 0; k < 64; ++k) {
    float a[4], b[3];
    #pragma unroll
    for (int i = 0; i < 4; ++i) a[i] = Hs[tr * 4 + i][k];
    #pragma unroll
    for (int j = 0; j < 3; ++j) b[j] = Ws[k][tc * 3 + j];
    #pragma unroll
    for (int i = 0; i < 4; ++i)
      #pragma unroll
      for (int j = 0; j < 3; ++j) acc[i][j] = fmaf(a[i], b[j], acc[i][j]);
  }
  #pragma unroll
  for (int i = 0; i < 4; ++i) {
    int rr = row0 + tr * 4 + i;
    if (rr >= M) continue;
    #pragma unroll
    for (int j = 0; j < 3; ++j) {
      int c = tc * 3 + j;
      float v = acc[i][j] + bs[c];
      if (c < 16) out[(size_t)rr * 16 + c] = v;
      else out[(size_t)M * 16 + (size_t)rr * 32 + (c - 16)] = v;
    }
  }
}

extern "C" void kernel_launch(void* const* d_in, const int* in_sizes, int n_in,
                              void* d_out, int out_size, void* d_ws, size_t ws_size,
                              hipStream_t stream) {
  const float* x    = (const float*)d_in[0];
  const int*   ei   = (const int*)d_in[1];
  const float* ew   = (const float*)d_in[2];
  const float* W1   = (const float*)d_in[3];
  const float* b1   = (const float*)d_in[4];
  const float* W2   = (const float*)d_in[5];
  const float* b2   = (const float*)d_in[6];
  const float* fW1  = (const float*)d_in[7];
  const float* fb1  = (const float*)d_in[8];
  const float* fW2  = (const float*)d_in[9];
  const float* fb2  = (const float*)d_in[10];
  float* out = (float*)d_out;

  const int N = in_sizes[0] / N_FEAT;
  const int E = in_sizes[2];
  const int* row = ei;
  const int* col = ei + E;

  char* ws = (char*)d_ws;
  float* dinv = (float*)ws;                                    // N floats
  float* bufA = (float*)(ws + 262144);                         // N*64 floats (xw)
  float* bufB = (float*)(ws + 262144 + (size_t)N * 64 * 4);    // N*64 floats (h)

  const int nbN  = (N + 255) / 256;
  const int nbE  = (E + 255) / 256;
  const int nbG  = (N + 63) / 64;
  const int nbI  = (N * 16 + 255) / 256;
  const int nbS  = (E * 64 + 255) / 256;

  // normalization (shared by both conv layers)
  k_deg_init<<<nbN, 256, 0, stream>>>(dinv, N);
  k_deg_acc<<<nbE, 256, 0, stream>>>(col, ew, dinv, E);
  k_dinv<<<nbN, 256, 0, stream>>>(dinv, N);

  // layer 1
  k_gemm64<N_FEAT, false><<<nbG, 256, 0, stream>>>(x, W1, bufA, N);
  k_init_h<<<nbI, 256, 0, stream>>>(bufA, dinv, b1, bufB, N);
  k_scatter<<<nbS, 256, 0, stream>>>(row, col, ew, dinv, bufA, bufB, E);

  // layer 2 (relu fused into A-load of gemm2)
  k_gemm64<N_HID, true><<<nbG, 256, 0, stream>>>(bufB, W2, bufA, N);
  k_init_h<<<nbI, 256, 0, stream>>>(bufA, dinv, b2, bufB, N);
  k_scatter<<<nbS, 256, 0, stream>>>(row, col, ew, dinv, bufA, bufB, E);

  // FC heads
  k_fc<<<nbG, 256, 0, stream>>>(bufB, fW1, fb1, fW2, fb2, out, N);
}

// Round 2
// 331.213 us; speedup vs baseline: 1.5468x; 1.5468x over previous
//
#include <hip/hip_runtime.h>
#include <cstdint>
#include <cstddef>

#define N_FEAT 512
#define N_HID 64
#define N_CLASS 16
#define N_CLUSTER 32

// ---------------- init: deg=1 (self-loop), cnt=0, cur=0 ----------------
__global__ void k_zero(float* deg, int* cnt, int* cur, int n) {
  int i = blockIdx.x * 256 + threadIdx.x;
  if (i < n) { deg[i] = 1.0f; cnt[i] = 0; cur[i] = 0; }
}

// ---------------- weighted degree + incoming-edge histogram ----------------
__global__ void k_degcnt(const int* __restrict__ col, const float* __restrict__ w,
                         float* __restrict__ deg, int* __restrict__ cnt, int E) {
  int i = blockIdx.x * 256 + threadIdx.x;
  if (i < E) {
    int c = col[i];
    atomicAdd(&deg[c], w[i]);
    atomicAdd(&cnt[c], 1);
  }
}

__global__ void k_dinv(float* deg, int n) {
  int i = blockIdx.x * 256 + threadIdx.x;
  if (i < n) { float d = deg[i]; deg[i] = (d > 0.f) ? rsqrtf(d) : 0.f; }
}

// ---------------- two-level exclusive scan of cnt -> off ----------------
__global__ __launch_bounds__(256) void k_scan1(const int* __restrict__ cnt,
                                               int* __restrict__ off,
                                               int* __restrict__ bsum, int n) {
  __shared__ int sh[256];
  int t = threadIdx.x;
  int i = blockIdx.x * 256 + t;
  int v = (i < n) ? cnt[i] : 0;
  sh[t] = v;
  __syncthreads();
  #pragma unroll
  for (int d = 1; d < 256; d <<= 1) {
    int x = 0;
    if (t >= d) x = sh[t - d];
    __syncthreads();
    if (t >= d) sh[t] += x;
    __syncthreads();
  }
  if (i < n) off[i] = sh[t] - v;           // exclusive
  if (t == 255) bsum[blockIdx.x] = sh[255];
}

__global__ __launch_bounds__(256) void k_scan2(const int* __restrict__ bsum,
                                               int* __restrict__ bsum2, int nb) {
  __shared__ int sh[256];
  int t = threadIdx.x;
  int v = (t < nb) ? bsum[t] : 0;
  sh[t] = v;
  __syncthreads();
  #pragma unroll
  for (int d = 1; d < 256; d <<= 1) {
    int x = 0;
    if (t >= d) x = sh[t - d];
    __syncthreads();
    if (t >= d) sh[t] += x;
    __syncthreads();
  }
  if (t < nb) bsum2[t] = sh[t] - v;        // exclusive
}

__global__ void k_scan3(int* __restrict__ off, const int* __restrict__ bsum2,
                        int n, int E) {
  int i = blockIdx.x * 256 + threadIdx.x;
  if (i < n) off[i] += bsum2[blockIdx.x];
  if (i == 0) off[n] = E;
}

// ---------------- fill CSR slots: per-target contiguous (src row, coef) ----------------
__global__ void k_fill(const int* __restrict__ rowi, const int* __restrict__ coli,
                       const float* __restrict__ w, const float* __restrict__ dinv,
                       const int* __restrict__ off, int* __restrict__ cur,
                       int* __restrict__ srcs, float* __restrict__ cofs, int E) {
  int e = blockIdx.x * 256 + threadIdx.x;
  if (e >= E) return;
  int r = rowi[e], c = coli[e];
  int p = off[c] + atomicAdd(&cur[c], 1);
  srcs[p] = r;
  cofs[p] = dinv[r] * w[e] * dinv[c];
}

// ---------------- tiled fp32 GEMM: C[M,64] = act(A[M,K]) @ B[K,64] ----------------
template<int K, bool RELU>
__global__ __launch_bounds__(256) void k_gemm64(
    const float* __restrict__ A, const float* __restrict__ B,
    float* __restrict__ C, int M) {
  __shared__ float As[64][68];
  __shared__ float Bs[64 * 64];
  const int t = threadIdx.x;
  const int row0 = blockIdx.x * 64;
  const int tr = t >> 4, tc = t & 15;
  float acc[4][4] = {{0.f}};

  for (int kc = 0; kc < K; kc += 64) {
    __syncthreads();
    #pragma unroll
    for (int i = 0; i < 4; ++i) {
      int f = t + i * 256;
      int r = f >> 4, k4 = f & 15;
      int row = row0 + r;
      float4 v = make_float4(0.f, 0.f, 0.f, 0.f);
      if (row < M) v = *(const float4*)&A[(size_t)row * K + kc + k4 * 4];
      if (RELU) {
        v.x = fmaxf(v.x, 0.f); v.y = fmaxf(v.y, 0.f);
        v.z = fmaxf(v.z, 0.f); v.w = fmaxf(v.w, 0.f);
      }
      *(float4*)&As[r][k4 * 4] = v;
    }
    #pragma unroll
    for (int i = 0; i < 4; ++i) {
      int f = t + i * 256;
      ((float4*)Bs)[f] = ((const float4*)(B + (size_t)kc * 64))[f];
    }
    __syncthreads();
    #pragma unroll 16
    for (int k = 0; k < 64; ++k) {
      float a0 = As[tr * 4 + 0][k];
      float a1 = As[tr * 4 + 1][k];
      float a2 = As[tr * 4 + 2][k];
      float a3 = As[tr * 4 + 3][k];
      float4 b = *(const float4*)&Bs[k * 64 + tc * 4];
      acc[0][0] = fmaf(a0, b.x, acc[0][0]); acc[0][1] = fmaf(a0, b.y, acc[0][1]);
      acc[0][2] = fmaf(a0, b.z, acc[0][2]); acc[0][3] = fmaf(a0, b.w, acc[0][3]);
      acc[1][0] = fmaf(a1, b.x, acc[1][0]); acc[1][1] = fmaf(a1, b.y, acc[1][1]);
      acc[1][2] = fmaf(a1, b.z, acc[1][2]); acc[1][3] = fmaf(a1, b.w, acc[1][3]);
      acc[2][0] = fmaf(a2, b.x, acc[2][0]); acc[2][1] = fmaf(a2, b.y, acc[2][1]);
      acc[2][2] = fmaf(a2, b.z, acc[2][2]); acc[2][3] = fmaf(a2, b.w, acc[2][3]);
      acc[3][0] = fmaf(a3, b.x, acc[3][0]); acc[3][1] = fmaf(a3, b.y, acc[3][1]);
      acc[3][2] = fmaf(a3, b.z, acc[3][2]); acc[3][3] = fmaf(a3, b.w, acc[3][3]);
    }
  }
  #pragma unroll
  for (int i = 0; i < 4; ++i) {
    int row = row0 + tr * 4 + i;
    if (row < M) {
      float4 v = make_float4(acc[i][0], acc[i][1], acc[i][2], acc[i][3]);
      *(float4*)&C[(size_t)row * 64 + tc * 4] = v;
    }
  }
}

// ---------------- gather conv: one wave per node, lane = feature dim ----------------
// h[c] = bias + dinv[c]^2 * xw[c] + sum_i cofs[i] * xw[srcs[i]]
__global__ __launch_bounds__(256) void k_gather(
    const int* __restrict__ off, const int* __restrict__ srcs,
    const float* __restrict__ cofs, const float* __restrict__ dinv,
    const float* __restrict__ xw, const float* __restrict__ bias,
    float* __restrict__ h, int n) {
  int gid = blockIdx.x * 256 + threadIdx.x;
  int c = gid >> 6, lane = gid & 63;
  if (c >= n) return;
  float s = dinv[c]; s *= s;
  float acc = fmaf(xw[(size_t)c * 64 + lane], s, bias[lane]);
  int i = off[c], s1 = off[c + 1];
  for (; i + 1 < s1; i += 2) {
    int r0 = srcs[i], r1 = srcs[i + 1];
    float c0 = cofs[i], c1 = cofs[i + 1];
    float v0 = xw[(size_t)r0 * 64 + lane];
    float v1 = xw[(size_t)r1 * 64 + lane];
    acc = fmaf(v0, c0, acc);
    acc = fmaf(v1, c1, acc);
  }
  if (i < s1) {
    acc = fmaf(xw[(size_t)srcs[i] * 64 + lane], cofs[i], acc);
  }
  h[(size_t)c * 64 + lane] = acc;
}

// ---------------- fused FC head ----------------
__global__ __launch_bounds__(256) void k_fc(
    const float* __restrict__ h,
    const float* __restrict__ fW1, const float* __restrict__ fb1,
    const float* __restrict__ fW2, const float* __restrict__ fb2,
    float* __restrict__ out, int M) {
  __shared__ float Hs[64][68];
  __shared__ float Ws[64][48];
  __shared__ float bs[48];
  const int t = threadIdx.x;
  const int row0 = blockIdx.x * 64;
  #pragma unroll
  for (int i = 0; i < 4; ++i) {
    int f = t + i * 256;
    int r = f >> 4, k4 = f & 15;
    int rr = row0 + r;
    float4 v = make_float4(0.f, 0.f, 0.f, 0.f);
    if (rr < M) v = *(const float4*)&h[(size_t)rr * 64 + k4 * 4];
    *(float4*)&Hs[r][k4 * 4] = v;
  }
  for (int f = t; f < 64 * 48; f += 256) {
    int k = f / 48, c = f - k * 48;
    Ws[k][c] = (c < 16) ? fW1[k * 16 + c] : fW2[k * 32 + (c - 16)];
  }
  if (t < 48) bs[t] = (t < 16) ? fb1[t] : fb2[t - 16];
  __syncthreads();
  const int tr = t >> 4, tc = t & 15;
  float acc[4][3] = {{0.f}};
  #pragma unroll 8
  for (int k = 0; k < 64; ++k) {
    float a[4], b[3];
    #pragma unroll
    for (int i = 0; i < 4; ++i) a[i] = Hs[tr * 4 + i][k];
    #pragma unroll
    for (int j = 0; j < 3; ++j) b[j] = Ws[k][tc * 3 + j];
    #pragma unroll
    for (int i = 0; i < 4; ++i)
      #pragma unroll
      for (int j = 0; j < 3; ++j) acc[i][j] = fmaf(a[i], b[j], acc[i][j]);
  }
  #pragma unroll
  for (int i = 0; i < 4; ++i) {
    int rr = row0 + tr * 4 + i;
    if (rr >= M) continue;
    #pragma unroll
    for (int j = 0; j < 3; ++j) {
      int c = tc * 3 + j;
      float v = acc[i][j] + bs[c];
      if (c < 16) out[(size_t)rr * 16 + c] = v;
      else out[(size_t)M * 16 + (size_t)rr * 32 + (c - 16)] = v;
    }
  }
}

extern "C" void kernel_launch(void* const* d_in, const int* in_sizes, int n_in,
                              void* d_out, int out_size, void* d_ws, size_t ws_size,
                              hipStream_t stream) {
  const float* x    = (const float*)d_in[0];
  const int*   ei   = (const int*)d_in[1];
  const float* ew   = (const float*)d_in[2];
  const float* W1   = (const float*)d_in[3];
  const float* b1   = (const float*)d_in[4];
  const float* W2   = (const float*)d_in[5];
  const float* b2   = (const float*)d_in[6];
  const float* fW1  = (const float*)d_in[7];
  const float* fb1  = (const float*)d_in[8];
  const float* fW2  = (const float*)d_in[9];
  const float* fb2  = (const float*)d_in[10];
  float* out = (float*)d_out;

  const int N = in_sizes[0] / N_FEAT;
  const int E = in_sizes[2];
  const int* row = ei;
  const int* col = ei + E;

  char* ws = (char*)d_ws;
  float* dinv  = (float*)(ws + 0x000000);                 // N floats
  int*   cnt   = (int*)  (ws + 0x040000);                 // N ints
  int*   off   = (int*)  (ws + 0x080000);                 // N+1 ints
  int*   bsum  = (int*)  (ws + 0x0C0000);                 // <=256 ints
  int*   bsum2 = (int*)  (ws + 0x0C1000);                 // <=256 ints
  int*   cur   = (int*)  (ws + 0x100000);                 // N ints
  int*   srcs  = (int*)  (ws + 0x140000);                 // E ints (3.2MB)
  float* cofs  = (float*)(ws + 0x540000);                 // E floats (3.2MB)
  float* bufA  = (float*)(ws + 0x940000);                 // N*64 floats (12.8MB)
  float* bufB  = (float*)(ws + 0x1640000);                // N*64 floats (12.8MB)

  const int nbN  = (N + 255) / 256;        // 196
  const int nbE  = (E + 255) / 256;
  const int nbG  = (N + 63) / 64;
  const int nbW  = (N * 64 + 255) / 256;   // wave-per-node kernels

  // ---- CSR build (shared by both conv layers) ----
  k_zero  <<<nbN, 256, 0, stream>>>(dinv, cnt, cur, N);
  k_degcnt<<<nbE, 256, 0, stream>>>(col, ew, dinv, cnt, E);
  k_dinv  <<<nbN, 256, 0, stream>>>(dinv, N);
  k_scan1 <<<nbN, 256, 0, stream>>>(cnt, off, bsum, N);
  k_scan2 <<<1,   256, 0, stream>>>(bsum, bsum2, nbN);
  k_scan3 <<<nbN, 256, 0, stream>>>(off, bsum2, N, E);
  k_fill  <<<nbE, 256, 0, stream>>>(row, col, ew, dinv, off, cur, srcs, cofs, E);

  // ---- layer 1 ----
  k_gemm64<N_FEAT, false><<<nbG, 256, 0, stream>>>(x, W1, bufA, N);
  k_gather<<<nbW, 256, 0, stream>>>(off, srcs, cofs, dinv, bufA, b1, bufB, N);

  // ---- layer 2 (relu fused into gemm2 A-load) ----
  k_gemm64<N_HID, true><<<nbG, 256, 0, stream>>>(bufB, W2, bufA, N);
  k_gather<<<nbW, 256, 0, stream>>>(off, srcs, cofs, dinv, bufA, b2, bufB, N);

  // ---- FC heads ----
  k_fc<<<nbG, 256, 0, stream>>>(bufB, fW1, fb1, fW2, fb2, out, N);
}

// Round 3
// 266.655 us; speedup vs baseline: 1.9213x; 1.2421x over previous
//
#include <hip/hip_runtime.h>
#include <cstdint>
#include <cstddef>

#define N_FEAT 512
#define N_HID 64
#define N_CLASS 16
#define N_CLUSTER 32
#define NPART 8          // privatized histogram partitions

// ---------------- packed degree/count histogram: one u64 atomic per edge ----------------
// hist[p][c] accumulates (count << 40) | sum(round(w * 2^24))
__global__ void k_degcnt2(const int* __restrict__ col, const float* __restrict__ w,
                          unsigned long long* __restrict__ hist, int H, int E) {
  int e = blockIdx.x * 256 + threadIdx.x;
  if (e >= E) return;
  int p = blockIdx.x & (NPART - 1);
  int c = col[e];
  unsigned long long fx = (unsigned long long)__float2uint_rn(w[e] * 16777216.0f);
  atomicAdd(&hist[(size_t)p * H + c], (1ull << 40) | fx);
}

// ---------------- fold partitions -> cnt, dinv ----------------
__global__ void k_reduce(const unsigned long long* __restrict__ hist, int H,
                         int* __restrict__ cnt, float* __restrict__ dinv, int n) {
  int i = blockIdx.x * 256 + threadIdx.x;
  if (i >= n) return;
  unsigned long long tot = 0;
  #pragma unroll
  for (int p = 0; p < NPART; ++p) tot += hist[(size_t)p * H + i];
  int c = (int)(tot >> 40);
  float wsum = (float)(tot & ((1ull << 40) - 1)) * 5.9604644775390625e-08f; // 2^-24
  float deg = 1.0f + wsum;
  cnt[i] = c;
  dinv[i] = rsqrtf(deg);   // deg >= 1 > 0 always
}

// ---------------- two-level exclusive scan of cnt -> off ----------------
__global__ __launch_bounds__(256) void k_scan1(const int* __restrict__ cnt,
                                               int* __restrict__ off,
                                               int* __restrict__ bsum, int n) {
  __shared__ int sh[256];
  int t = threadIdx.x;
  int i = blockIdx.x * 256 + t;
  int v = (i < n) ? cnt[i] : 0;
  sh[t] = v;
  __syncthreads();
  #pragma unroll
  for (int d = 1; d < 256; d <<= 1) {
    int x = 0;
    if (t >= d) x = sh[t - d];
    __syncthreads();
    if (t >= d) sh[t] += x;
    __syncthreads();
  }
  if (i < n) off[i] = sh[t] - v;           // exclusive
  if (t == 255) bsum[blockIdx.x] = sh[255];
}

__global__ __launch_bounds__(256) void k_scan2(const int* __restrict__ bsum,
                                               int* __restrict__ bsum2, int nb) {
  __shared__ int sh[256];
  int t = threadIdx.x;
  int v = (t < nb) ? bsum[t] : 0;
  sh[t] = v;
  __syncthreads();
  #pragma unroll
  for (int d = 1; d < 256; d <<= 1) {
    int x = 0;
    if (t >= d) x = sh[t - d];
    __syncthreads();
    if (t >= d) sh[t] += x;
    __syncthreads();
  }
  if (t < nb) bsum2[t] = sh[t] - v;        // exclusive
}

// ---------------- scan fixup + init per-partition cursors ----------------
__global__ void k_scan3_initcur(int* __restrict__ off, const int* __restrict__ bsum2,
                                const unsigned long long* __restrict__ hist, int H,
                                int* __restrict__ cur, int n, int E) {
  int i = blockIdx.x * 256 + threadIdx.x;
  if (i < n) {
    int o = off[i] + bsum2[blockIdx.x];
    off[i] = o;
    int running = o;
    #pragma unroll
    for (int p = 0; p < NPART; ++p) {
      cur[(size_t)p * H + i] = running;
      running += (int)(hist[(size_t)p * H + i] >> 40);
    }
  }
  if (i == 0) off[n] = E;
}

// ---------------- fill CSR slots (privatized cursors) ----------------
__global__ void k_fill2(const int* __restrict__ rowi, const int* __restrict__ coli,
                        const float* __restrict__ w, const float* __restrict__ dinv,
                        int* __restrict__ cur, int H,
                        int* __restrict__ srcs, float* __restrict__ cofs, int E) {
  int e = blockIdx.x * 256 + threadIdx.x;
  if (e >= E) return;
  int p = blockIdx.x & (NPART - 1);       // must match k_degcnt2's mapping
  int r = rowi[e], c = coli[e];
  int pos = atomicAdd(&cur[(size_t)p * H + c], 1);
  srcs[pos] = r;
  cofs[pos] = dinv[r] * w[e] * dinv[c];
}

// ---------------- tiled fp32 GEMM: C[M,64] = act(A[M,K]) @ B[K,64] ----------------
template<int K, bool RELU>
__global__ __launch_bounds__(256) void k_gemm64(
    const float* __restrict__ A, const float* __restrict__ B,
    float* __restrict__ C, int M) {
  __shared__ float As[64][68];
  __shared__ float Bs[64 * 64];
  const int t = threadIdx.x;
  const int row0 = blockIdx.x * 64;
  const int tr = t >> 4, tc = t & 15;
  float acc[4][4] = {{0.f}};

  for (int kc = 0; kc < K; kc += 64) {
    __syncthreads();
    #pragma unroll
    for (int i = 0; i < 4; ++i) {
      int f = t + i * 256;
      int r = f >> 4, k4 = f & 15;
      int row = row0 + r;
      float4 v = make_float4(0.f, 0.f, 0.f, 0.f);
      if (row < M) v = *(const float4*)&A[(size_t)row * K + kc + k4 * 4];
      if (RELU) {
        v.x = fmaxf(v.x, 0.f); v.y = fmaxf(v.y, 0.f);
        v.z = fmaxf(v.z, 0.f); v.w = fmaxf(v.w, 0.f);
      }
      *(float4*)&As[r][k4 * 4] = v;
    }
    #pragma unroll
    for (int i = 0; i < 4; ++i) {
      int f = t + i * 256;
      ((float4*)Bs)[f] = ((const float4*)(B + (size_t)kc * 64))[f];
    }
    __syncthreads();
    #pragma unroll 16
    for (int k = 0; k < 64; ++k) {
      float a0 = As[tr * 4 + 0][k];
      float a1 = As[tr * 4 + 1][k];
      float a2 = As[tr * 4 + 2][k];
      float a3 = As[tr * 4 + 3][k];
      float4 b = *(const float4*)&Bs[k * 64 + tc * 4];
      acc[0][0] = fmaf(a0, b.x, acc[0][0]); acc[0][1] = fmaf(a0, b.y, acc[0][1]);
      acc[0][2] = fmaf(a0, b.z, acc[0][2]); acc[0][3] = fmaf(a0, b.w, acc[0][3]);
      acc[1][0] = fmaf(a1, b.x, acc[1][0]); acc[1][1] = fmaf(a1, b.y, acc[1][1]);
      acc[1][2] = fmaf(a1, b.z, acc[1][2]); acc[1][3] = fmaf(a1, b.w, acc[1][3]);
      acc[2][0] = fmaf(a2, b.x, acc[2][0]); acc[2][1] = fmaf(a2, b.y, acc[2][1]);
      acc[2][2] = fmaf(a2, b.z, acc[2][2]); acc[2][3] = fmaf(a2, b.w, acc[2][3]);
      acc[3][0] = fmaf(a3, b.x, acc[3][0]); acc[3][1] = fmaf(a3, b.y, acc[3][1]);
      acc[3][2] = fmaf(a3, b.z, acc[3][2]); acc[3][3] = fmaf(a3, b.w, acc[3][3]);
    }
  }
  #pragma unroll
  for (int i = 0; i < 4; ++i) {
    int row = row0 + tr * 4 + i;
    if (row < M) {
      float4 v = make_float4(acc[i][0], acc[i][1], acc[i][2], acc[i][3]);
      *(float4*)&C[(size_t)row * 64 + tc * 4] = v;
    }
  }
}

// ---------------- gather conv: one wave per node, lane = feature dim ----------------
__global__ __launch_bounds__(256) void k_gather(
    const int* __restrict__ off, const int* __restrict__ srcs,
    const float* __restrict__ cofs, const float* __restrict__ dinv,
    const float* __restrict__ xw, const float* __restrict__ bias,
    float* __restrict__ h, int n) {
  int gid = blockIdx.x * 256 + threadIdx.x;
  int c = gid >> 6, lane = gid & 63;
  if (c >= n) return;
  float s = dinv[c]; s *= s;
  float acc = fmaf(xw[(size_t)c * 64 + lane], s, bias[lane]);
  int i = off[c], end = off[c + 1];
  for (; i + 3 < end; i += 4) {
    int r0 = srcs[i], r1 = srcs[i + 1], r2 = srcs[i + 2], r3 = srcs[i + 3];
    float c0 = cofs[i], c1 = cofs[i + 1], c2 = cofs[i + 2], c3 = cofs[i + 3];
    float v0 = xw[(size_t)r0 * 64 + lane];
    float v1 = xw[(size_t)r1 * 64 + lane];
    float v2 = xw[(size_t)r2 * 64 + lane];
    float v3 = xw[(size_t)r3 * 64 + lane];
    acc = fmaf(v0, c0, acc);
    acc = fmaf(v1, c1, acc);
    acc = fmaf(v2, c2, acc);
    acc = fmaf(v3, c3, acc);
  }
  for (; i < end; ++i) {
    acc = fmaf(xw[(size_t)srcs[i] * 64 + lane], cofs[i], acc);
  }
  h[(size_t)c * 64 + lane] = acc;
}

// ---------------- fused FC head ----------------
__global__ __launch_bounds__(256) void k_fc(
    const float* __restrict__ h,
    const float* __restrict__ fW1, const float* __restrict__ fb1,
    const float* __restrict__ fW2, const float* __restrict__ fb2,
    float* __restrict__ out, int M) {
  __shared__ float Hs[64][68];
  __shared__ float Ws[64][48];
  __shared__ float bs[48];
  const int t = threadIdx.x;
  const int row0 = blockIdx.x * 64;
  #pragma unroll
  for (int i = 0; i < 4; ++i) {
    int f = t + i * 256;
    int r = f >> 4, k4 = f & 15;
    int rr = row0 + r;
    float4 v = make_float4(0.f, 0.f, 0.f, 0.f);
    if (rr < M) v = *(const float4*)&h[(size_t)rr * 64 + k4 * 4];
    *(float4*)&Hs[r][k4 * 4] = v;
  }
  for (int f = t; f < 64 * 48; f += 256) {
    int k = f / 48, c = f - k * 48;
    Ws[k][c] = (c < 16) ? fW1[k * 16 + c] : fW2[k * 32 + (c - 16)];
  }
  if (t < 48) bs[t] = (t < 16) ? fb1[t] : fb2[t - 16];
  __syncthreads();
  const int tr = t >> 4, tc = t & 15;
  float acc[4][3] = {{0.f}};
  #pragma unroll 8
  for (int k = 0; k < 64; ++k) {
    float a[4], b[3];
    #pragma unroll
    for (int i = 0; i < 4; ++i) a[i] = Hs[tr * 4 + i][k];
    #pragma unroll
    for (int j = 0; j < 3; ++j) b[j] = Ws[k][tc * 3 + j];
    #pragma unroll
    for (int i = 0; i < 4; ++i)
      #pragma unroll
      for (int j = 0; j < 3; ++j) acc[i][j] = fmaf(a[i], b[j], acc[i][j]);
  }
  #pragma unroll
  for (int i = 0; i < 4; ++i) {
    int rr = row0 + tr * 4 + i;
    if (rr >= M) continue;
    #pragma unroll
    for (int j = 0; j < 3; ++j) {
      int c = tc * 3 + j;
      float v = acc[i][j] + bs[c];
      if (c < 16) out[(size_t)rr * 16 + c] = v;
      else out[(size_t)M * 16 + (size_t)rr * 32 + (c - 16)] = v;
    }
  }
}

extern "C" void kernel_launch(void* const* d_in, const int* in_sizes, int n_in,
                              void* d_out, int out_size, void* d_ws, size_t ws_size,
                              hipStream_t stream) {
  const float* x    = (const float*)d_in[0];
  const int*   ei   = (const int*)d_in[1];
  const float* ew   = (const float*)d_in[2];
  const float* W1   = (const float*)d_in[3];
  const float* b1   = (const float*)d_in[4];
  const float* W2   = (const float*)d_in[5];
  const float* b2   = (const float*)d_in[6];
  const float* fW1  = (const float*)d_in[7];
  const float* fb1  = (const float*)d_in[8];
  const float* fW2  = (const float*)d_in[9];
  const float* fb2  = (const float*)d_in[10];
  float* out = (float*)d_out;

  const int N = in_sizes[0] / N_FEAT;
  const int E = in_sizes[2];
  const int H = (N + 63) & ~63;            // padded histogram stride
  const int* row = ei;
  const int* col = ei + E;

  char* ws = (char*)d_ws;
  float*              dinv = (float*)(ws + 0x000000);              // N f
  int*                cnt  = (int*)  (ws + 0x040000);              // N i
  int*                off  = (int*)  (ws + 0x080000);              // N+1 i
  int*                bsum = (int*)  (ws + 0x0C0000);
  int*                bsum2= (int*)  (ws + 0x0C1000);
  unsigned long long* hist = (unsigned long long*)(ws + 0x100000); // 8*H u64 (3.2MB)
  int*                cur  = (int*)  (ws + 0x500000);              // 8*H i (1.6MB)
  int*                srcs = (int*)  (ws + 0x6C0000);              // E i (3.2MB)
  float*              cofs = (float*)(ws + 0xA00000);              // E f (3.2MB)
  float*              bufA = (float*)(ws + 0xD40000);              // N*64 f (12.8MB)
  float*              bufB = (float*)(ws + 0x1980000);             // N*64 f (12.8MB)

  const int nbN  = (N + 255) / 256;
  const int nbE  = (E + 255) / 256;
  const int nbG  = (N + 63) / 64;
  const int nbW  = (N * 64 + 255) / 256;

  // ---- CSR build (shared by both conv layers) ----
  hipMemsetAsync(hist, 0, (size_t)NPART * H * 8, stream);
  k_degcnt2<<<nbE, 256, 0, stream>>>(col, ew, hist, H, E);
  k_reduce <<<nbN, 256, 0, stream>>>(hist, H, cnt, dinv, N);
  k_scan1  <<<nbN, 256, 0, stream>>>(cnt, off, bsum, N);
  k_scan2  <<<1,   256, 0, stream>>>(bsum, bsum2, nbN);
  k_scan3_initcur<<<nbN, 256, 0, stream>>>(off, bsum2, hist, H, cur, N, E);
  k_fill2  <<<nbE, 256, 0, stream>>>(row, col, ew, dinv, cur, H, srcs, cofs, E);

  // ---- layer 1 ----
  k_gemm64<N_FEAT, false><<<nbG, 256, 0, stream>>>(x, W1, bufA, N);
  k_gather<<<nbW, 256, 0, stream>>>(off, srcs, cofs, dinv, bufA, b1, bufB, N);

  // ---- layer 2 (relu fused into gemm2 A-load) ----
  k_gemm64<N_HID, true><<<nbG, 256, 0, stream>>>(bufB, W2, bufA, N);
  k_gather<<<nbW, 256, 0, stream>>>(off, srcs, cofs, dinv, bufA, b2, bufB, N);

  // ---- FC heads ----
  k_fc<<<nbG, 256, 0, stream>>>(bufB, fW1, fb1, fW2, fb2, out, N);
}

// Round 4
// 236.789 us; speedup vs baseline: 2.1636x; 1.1261x over previous
//
#include <hip/hip_runtime.h>
#include <hip/hip_bf16.h>
#include <cstdint>
#include <cstddef>

#define N_FEAT 512
#define N_HID 64
#define N_CLASS 16
#define N_CLUSTER 32
#define NPART 8          // privatized histogram partitions

typedef short short8 __attribute__((ext_vector_type(8)));
typedef float floatx4 __attribute__((ext_vector_type(4)));

__device__ __forceinline__ short f2bf(float f) {
  __hip_bfloat16 h = __float2bfloat16(f);
  return *reinterpret_cast<short*>(&h);
}

// ---------------- packed degree/count histogram: one u64 atomic per edge ----------------
__global__ void k_degcnt2(const int* __restrict__ col, const float* __restrict__ w,
                          unsigned long long* __restrict__ hist, int H, int E) {
  int e = blockIdx.x * 256 + threadIdx.x;
  if (e >= E) return;
  int p = blockIdx.x & (NPART - 1);
  int c = col[e];
  unsigned long long fx = (unsigned long long)__float2uint_rn(w[e] * 16777216.0f);
  atomicAdd(&hist[(size_t)p * H + c], (1ull << 40) | fx);
}

// ---------------- fold partitions -> cnt, dinv ----------------
__global__ void k_reduce(const unsigned long long* __restrict__ hist, int H,
                         int* __restrict__ cnt, float* __restrict__ dinv, int n) {
  int i = blockIdx.x * 256 + threadIdx.x;
  if (i >= n) return;
  unsigned long long tot = 0;
  #pragma unroll
  for (int p = 0; p < NPART; ++p) tot += hist[(size_t)p * H + i];
  int c = (int)(tot >> 40);
  float wsum = (float)(tot & ((1ull << 40) - 1)) * 5.9604644775390625e-08f; // 2^-24
  cnt[i] = c;
  dinv[i] = rsqrtf(1.0f + wsum);
}

// ---------------- two-level exclusive scan of cnt -> off ----------------
__global__ __launch_bounds__(256) void k_scan1(const int* __restrict__ cnt,
                                               int* __restrict__ off,
                                               int* __restrict__ bsum, int n) {
  __shared__ int sh[256];
  int t = threadIdx.x;
  int i = blockIdx.x * 256 + t;
  int v = (i < n) ? cnt[i] : 0;
  sh[t] = v;
  __syncthreads();
  #pragma unroll
  for (int d = 1; d < 256; d <<= 1) {
    int x = 0;
    if (t >= d) x = sh[t - d];
    __syncthreads();
    if (t >= d) sh[t] += x;
    __syncthreads();
  }
  if (i < n) off[i] = sh[t] - v;
  if (t == 255) bsum[blockIdx.x] = sh[255];
}

__global__ __launch_bounds__(256) void k_scan2(const int* __restrict__ bsum,
                                               int* __restrict__ bsum2, int nb) {
  __shared__ int sh[256];
  int t = threadIdx.x;
  int v = (t < nb) ? bsum[t] : 0;
  sh[t] = v;
  __syncthreads();
  #pragma unroll
  for (int d = 1; d < 256; d <<= 1) {
    int x = 0;
    if (t >= d) x = sh[t - d];
    __syncthreads();
    if (t >= d) sh[t] += x;
    __syncthreads();
  }
  if (t < nb) bsum2[t] = sh[t] - v;
}

__global__ void k_scan3_initcur(int* __restrict__ off, const int* __restrict__ bsum2,
                                const unsigned long long* __restrict__ hist, int H,
                                int* __restrict__ cur, int n, int E) {
  int i = blockIdx.x * 256 + threadIdx.x;
  if (i < n) {
    int o = off[i] + bsum2[blockIdx.x];
    off[i] = o;
    int running = o;
    #pragma unroll
    for (int p = 0; p < NPART; ++p) {
      cur[(size_t)p * H + i] = running;
      running += (int)(hist[(size_t)p * H + i] >> 40);
    }
  }
  if (i == 0) off[n] = E;
}

// ---------------- fill CSR slots (privatized cursors) ----------------
__global__ void k_fill2(const int* __restrict__ rowi, const int* __restrict__ coli,
                        const float* __restrict__ w, const float* __restrict__ dinv,
                        int* __restrict__ cur, int H,
                        int* __restrict__ srcs, float* __restrict__ cofs, int E) {
  int e = blockIdx.x * 256 + threadIdx.x;
  if (e >= E) return;
  int p = blockIdx.x & (NPART - 1);
  int r = rowi[e], c = coli[e];
  int pos = atomicAdd(&cur[(size_t)p * H + c], 1);
  srcs[pos] = r;
  cofs[pos] = dinv[r] * w[e] * dinv[c];
}

// ---------------- W[K][64] fp32 -> Bt[64][K+8] bf16 (transposed, padded) ----------------
__global__ void k_prepB(const float* __restrict__ W, short* __restrict__ Bt,
                        int K, int ncol) {
  int idx = blockIdx.x * 256 + threadIdx.x;
  int kg = K >> 3;
  if (idx >= ncol * kg) return;
  int c = idx / kg, g = idx - c * kg;
  short8 v;
  #pragma unroll
  for (int j = 0; j < 8; ++j) v[j] = f2bf(W[(size_t)(g * 8 + j) * ncol + c]);
  *(short8*)(Bt + (size_t)c * (K + 8) + g * 8) = v;
}

// ---------------- MFMA GEMM: C[M,64] = act(A[M,K]) @ B[K,64], bf16 inputs fp32 accum ----
// LDS-free: A fragments direct from global (A rows have zero reuse),
// B fragments from pre-transposed bf16 Bt[col][k] (L2-resident).
template<int K, bool RELU>
__global__ __launch_bounds__(256) void k_mfma(
    const float* __restrict__ A, const short* __restrict__ Bt,
    float* __restrict__ C, int M) {
  constexpr int BS = K + 8;
  const int lane = threadIdx.x & 63;
  const int wid = threadIdx.x >> 6;
  const int rbase = blockIdx.x * 64 + wid * 16;
  const int r = rbase + (lane & 15);
  const int rc = (r < M) ? r : (M - 1);          // clamp: only its own D-row is garbage
  const int klo = (lane >> 4) * 8;
  const float* arow = A + (size_t)rc * K + klo;
  const short* bbase = Bt + (size_t)(lane & 15) * BS + klo;

  floatx4 acc[4];
  #pragma unroll
  for (int j = 0; j < 4; ++j) acc[j] = (floatx4){0.f, 0.f, 0.f, 0.f};

  #pragma unroll
  for (int kc = 0; kc < K; kc += 32) {
    float4 a0 = *(const float4*)(arow + kc);
    float4 a1 = *(const float4*)(arow + kc + 4);
    if (RELU) {
      a0.x = fmaxf(a0.x, 0.f); a0.y = fmaxf(a0.y, 0.f);
      a0.z = fmaxf(a0.z, 0.f); a0.w = fmaxf(a0.w, 0.f);
      a1.x = fmaxf(a1.x, 0.f); a1.y = fmaxf(a1.y, 0.f);
      a1.z = fmaxf(a1.z, 0.f); a1.w = fmaxf(a1.w, 0.f);
    }
    short8 af;
    af[0] = f2bf(a0.x); af[1] = f2bf(a0.y); af[2] = f2bf(a0.z); af[3] = f2bf(a0.w);
    af[4] = f2bf(a1.x); af[5] = f2bf(a1.y); af[6] = f2bf(a1.z); af[7] = f2bf(a1.w);
    #pragma unroll
    for (int j = 0; j < 4; ++j) {
      short8 bf = *(const short8*)(bbase + (size_t)j * 16 * BS + kc);
      acc[j] = __builtin_amdgcn_mfma_f32_16x16x32_bf16(af, bf, acc[j], 0, 0, 0);
    }
  }

  const int srow = rbase + (lane >> 4) * 4;
  const int scol = lane & 15;
  #pragma unroll
  for (int i = 0; i < 4; ++i) {
    int rr = srow + i;
    if (rr < M) {
      #pragma unroll
      for (int j = 0; j < 4; ++j)
        C[(size_t)rr * 64 + j * 16 + scol] = acc[j][i];
    }
  }
}

// ---------------- gather conv: one wave per node, lane = feature dim ----------------
__global__ __launch_bounds__(256) void k_gather(
    const int* __restrict__ off, const int* __restrict__ srcs,
    const float* __restrict__ cofs, const float* __restrict__ dinv,
    const float* __restrict__ xw, const float* __restrict__ bias,
    float* __restrict__ h, int n) {
  int gid = blockIdx.x * 256 + threadIdx.x;
  int c = gid >> 6, lane = gid & 63;
  if (c >= n) return;
  float s = dinv[c]; s *= s;
  float acc = fmaf(xw[(size_t)c * 64 + lane], s, bias[lane]);
  int i = off[c], end = off[c + 1];
  for (; i + 3 < end; i += 4) {
    int r0 = srcs[i], r1 = srcs[i + 1], r2 = srcs[i + 2], r3 = srcs[i + 3];
    float c0 = cofs[i], c1 = cofs[i + 1], c2 = cofs[i + 2], c3 = cofs[i + 3];
    float v0 = xw[(size_t)r0 * 64 + lane];
    float v1 = xw[(size_t)r1 * 64 + lane];
    float v2 = xw[(size_t)r2 * 64 + lane];
    float v3 = xw[(size_t)r3 * 64 + lane];
    acc = fmaf(v0, c0, acc);
    acc = fmaf(v1, c1, acc);
    acc = fmaf(v2, c2, acc);
    acc = fmaf(v3, c3, acc);
  }
  for (; i < end; ++i) {
    acc = fmaf(xw[(size_t)srcs[i] * 64 + lane], cofs[i], acc);
  }
  h[(size_t)c * 64 + lane] = acc;
}

// ---------------- fused FC head ----------------
__global__ __launch_bounds__(256) void k_fc(
    const float* __restrict__ h,
    const float* __restrict__ fW1, const float* __restrict__ fb1,
    const float* __restrict__ fW2, const float* __restrict__ fb2,
    float* __restrict__ out, int M) {
  __shared__ float Hs[64][68];
  __shared__ float Ws[64][48];
  __shared__ float bs[48];
  const int t = threadIdx.x;
  const int row0 = blockIdx.x * 64;
  #pragma unroll
  for (int i = 0; i < 4; ++i) {
    int f = t + i * 256;
    int r = f >> 4, k4 = f & 15;
    int rr = row0 + r;
    float4 v = make_float4(0.f, 0.f, 0.f, 0.f);
    if (rr < M) v = *(const float4*)&h[(size_t)rr * 64 + k4 * 4];
    *(float4*)&Hs[r][k4 * 4] = v;
  }
  for (int f = t; f < 64 * 48; f += 256) {
    int k = f / 48, c = f - k * 48;
    Ws[k][c] = (c < 16) ? fW1[k * 16 + c] : fW2[k * 32 + (c - 16)];
  }
  if (t < 48) bs[t] = (t < 16) ? fb1[t] : fb2[t - 16];
  __syncthreads();
  const int tr = t >> 4, tc = t & 15;
  float acc[4][3] = {{0.f}};
  #pragma unroll 8
  for (int k = 0; k < 64; ++k) {
    float a[4], b[3];
    #pragma unroll
    for (int i = 0; i < 4; ++i) a[i] = Hs[tr * 4 + i][k];
    #pragma unroll
    for (int j = 0; j < 3; ++j) b[j] = Ws[k][tc * 3 + j];
    #pragma unroll
    for (int i = 0; i < 4; ++i)
      #pragma unroll
      for (int j = 0; j < 3; ++j) acc[i][j] = fmaf(a[i], b[j], acc[i][j]);
  }
  #pragma unroll
  for (int i = 0; i < 4; ++i) {
    int rr = row0 + tr * 4 + i;
    if (rr >= M) continue;
    #pragma unroll
    for (int j = 0; j < 3; ++j) {
      int c = tc * 3 + j;
      float v = acc[i][j] + bs[c];
      if (c < 16) out[(size_t)rr * 16 + c] = v;
      else out[(size_t)M * 16 + (size_t)rr * 32 + (c - 16)] = v;
    }
  }
}

extern "C" void kernel_launch(void* const* d_in, const int* in_sizes, int n_in,
                              void* d_out, int out_size, void* d_ws, size_t ws_size,
                              hipStream_t stream) {
  const float* x    = (const float*)d_in[0];
  const int*   ei   = (const int*)d_in[1];
  const float* ew   = (const float*)d_in[2];
  const float* W1   = (const float*)d_in[3];
  const float* b1   = (const float*)d_in[4];
  const float* W2   = (const float*)d_in[5];
  const float* b2   = (const float*)d_in[6];
  const float* fW1  = (const float*)d_in[7];
  const float* fb1  = (const float*)d_in[8];
  const float* fW2  = (const float*)d_in[9];
  const float* fb2  = (const float*)d_in[10];
  float* out = (float*)d_out;

  const int N = in_sizes[0] / N_FEAT;
  const int E = in_sizes[2];
  const int H = (N + 63) & ~63;
  const int* row = ei;
  const int* col = ei + E;

  char* ws = (char*)d_ws;
  float*              dinv = (float*)(ws + 0x000000);              // N f
  int*                cnt  = (int*)  (ws + 0x040000);              // N i
  int*                off  = (int*)  (ws + 0x080000);              // N+1 i
  int*                bsum = (int*)  (ws + 0x0C0000);
  int*                bsum2= (int*)  (ws + 0x0C1000);
  short*              Bt1  = (short*)(ws + 0x0C8000);              // 64*(512+8) bf16 (66.6KB)
  short*              Bt2  = (short*)(ws + 0x0DA000);              // 64*(64+8) bf16 (9.2KB)
  unsigned long long* hist = (unsigned long long*)(ws + 0x100000); // 8*H u64 (3.2MB)
  int*                cur  = (int*)  (ws + 0x500000);              // 8*H i (1.6MB)
  int*                srcs = (int*)  (ws + 0x6C0000);              // E i (3.2MB)
  float*              cofs = (float*)(ws + 0xA00000);              // E f (3.2MB)
  float*              bufA = (float*)(ws + 0xD40000);              // N*64 f (12.8MB)
  float*              bufB = (float*)(ws + 0x1980000);             // N*64 f (12.8MB)

  const int nbN  = (N + 255) / 256;
  const int nbE  = (E + 255) / 256;
  const int nbG  = (N + 63) / 64;
  const int nbW  = (N * 64 + 255) / 256;

  // ---- weight pre-transpose (bf16) ----
  k_prepB<<<16, 256, 0, stream>>>(W1, Bt1, N_FEAT, 64);
  k_prepB<<<2,  256, 0, stream>>>(W2, Bt2, N_HID, 64);

  // ---- CSR build (shared by both conv layers) ----
  hipMemsetAsync(hist, 0, (size_t)NPART * H * 8, stream);
  k_degcnt2<<<nbE, 256, 0, stream>>>(col, ew, hist, H, E);
  k_reduce <<<nbN, 256, 0, stream>>>(hist, H, cnt, dinv, N);
  k_scan1  <<<nbN, 256, 0, stream>>>(cnt, off, bsum, N);
  k_scan2  <<<1,   256, 0, stream>>>(bsum, bsum2, nbN);
  k_scan3_initcur<<<nbN, 256, 0, stream>>>(off, bsum2, hist, H, cur, N, E);
  k_fill2  <<<nbE, 256, 0, stream>>>(row, col, ew, dinv, cur, H, srcs, cofs, E);

  // ---- layer 1 ----
  k_mfma<N_FEAT, false><<<nbG, 256, 0, stream>>>(x, Bt1, bufA, N);
  k_gather<<<nbW, 256, 0, stream>>>(off, srcs, cofs, dinv, bufA, b1, bufB, N);

  // ---- layer 2 (relu fused into A-load cvt) ----
  k_mfma<N_HID, true><<<nbG, 256, 0, stream>>>(bufB, Bt2, bufA, N);
  k_gather<<<nbW, 256, 0, stream>>>(off, srcs, cofs, dinv, bufA, b2, bufB, N);

  // ---- FC heads ----
  k_fc<<<nbG, 256, 0, stream>>>(bufB, fW1, fb1, fW2, fb2, out, N);
}